// Round 1
// baseline (765.797 us; speedup 1.0000x reference)
//
#include <hip/hip_runtime.h>
#include <math.h>

#define EPSV 1e-4f
#define NG 8
#define LL 64
#define NB 32
#define CC 512
#define HWS 3136
#define MTOT (NB * HWS)
#define NPI 19
#define NTILES 49

__device__ __forceinline__ float wave_sum(float v) {
#pragma unroll
  for (int off = 32; off > 0; off >>= 1) v += __shfl_xor(v, off, 64);
  return v;
}

// ---------------------------------------------------------------------------
// Kernel A: fused channel sums + raw second moments, per (group, n, part).
// LDS tile [m][ch] (pad 68 keeps float4 rows 16B aligned). Deterministic:
// partials written to ws, reduced in fixed order by k_cov.
// ---------------------------------------------------------------------------
__global__ __launch_bounds__(256, 2) void k_moments(const float* __restrict__ x,
                                                    float* __restrict__ prods,
                                                    float* __restrict__ sums,
                                                    int nparts) {
  const int g = blockIdx.x, n = blockIdx.y, h = blockIdx.z;
  const int tid = threadIdx.x;
  const int q = tid >> 6, l = tid & 63;   // load mapping
  const int ty = tid >> 4, tx = tid & 15; // compute mapping (16x16 tiles of 4x4)
  __shared__ float xs[64][68];
  const float* xp = x + ((size_t)(n * CC + g * LL)) * HWS;

  float acc[4][4];
#pragma unroll
  for (int a = 0; a < 4; ++a)
#pragma unroll
    for (int b = 0; b < 4; ++b) acc[a][b] = 0.f;
  float csum[16];
#pragma unroll
  for (int r = 0; r < 16; ++r) csum[r] = 0.f;

  const int tpp = (NTILES + nparts - 1) / nparts;
  const int t0 = h * tpp;
  const int t1 = (t0 + tpp < NTILES) ? (t0 + tpp) : NTILES;

  for (int t = t0; t < t1; ++t) {
    const int hw0 = t * 64;
    __syncthreads();
#pragma unroll
    for (int r = 0; r < 16; ++r) {
      const int ch = r * 4 + q;
      float v = xp[ch * HWS + hw0 + l]; // coalesced along hw
      xs[l][ch] = v;
      csum[r] += v;
    }
    __syncthreads();
#pragma unroll 4
    for (int mm = 0; mm < 64; ++mm) {
      const float4* row = (const float4*)(&xs[mm][0]);
      float4 av = row[ty];
      float4 bv = row[tx];
      float a4[4] = {av.x, av.y, av.z, av.w};
      float b4[4] = {bv.x, bv.y, bv.z, bv.w};
#pragma unroll
      for (int ii = 0; ii < 4; ++ii)
#pragma unroll
        for (int jj = 0; jj < 4; ++jj) acc[ii][jj] += a4[ii] * b4[jj];
    }
  }

  const int p = n * nparts + h;
  float* pp = prods + ((size_t)(g * NB * nparts + p)) * 4096;
#pragma unroll
  for (int ii = 0; ii < 4; ++ii) {
    *(float4*)&pp[(ty * 4 + ii) * 64 + tx * 4] =
        make_float4(acc[ii][0], acc[ii][1], acc[ii][2], acc[ii][3]);
  }
#pragma unroll
  for (int r = 0; r < 16; ++r) {
    float s = wave_sum(csum[r]); // sum over l within this wave (q fixed)
    if (l == 0) sums[((size_t)(g * NB * nparts + p)) * 64 + r * 4 + q] = s;
  }
}

// ---------------------------------------------------------------------------
// Kernel B: reduce partials (fixed order) -> mu, cov = S/M - mu_i mu_j + eps*I
// ---------------------------------------------------------------------------
__global__ __launch_bounds__(256) void k_cov(const float* __restrict__ prods,
                                             const float* __restrict__ sums,
                                             float* __restrict__ mu,
                                             float* __restrict__ cov,
                                             int nparts) {
  const int g = blockIdx.x;
  const int tid = threadIdx.x;
  const int P = NB * nparts;
  __shared__ float mu_sh[64];
  if (tid < 64) {
    float s = 0.f;
    for (int p = 0; p < P; ++p) s += sums[((size_t)(g * P + p)) * 64 + tid];
    float m = s / (float)MTOT;
    mu_sh[tid] = m;
    mu[g * 64 + tid] = m;
  }
  __syncthreads();
#pragma unroll
  for (int k = 0; k < 16; ++k) {
    const int e = tid + k * 256;
    const int i = e >> 6, j = e & 63;
    float s = 0.f;
    for (int p = 0; p < P; ++p) s += prods[((size_t)(g * P + p)) * 4096 + e];
    float cv = s / (float)MTOT - mu_sh[i] * mu_sh[j] + (i == j ? EPSV : 0.f);
    cov[(size_t)g * 4096 + e] = cv;
  }
}

// ---------------------------------------------------------------------------
// Kernel C: sequential power iteration + deflation. One wave per group.
// Lane r holds row r of A and of the subspace in VGPRs; v lives in LDS
// (same-address reads = broadcast, conflict-free). Early break is exactly
// equivalent to the reference's sticky 'stopped' flag.
// ---------------------------------------------------------------------------
__device__ __forceinline__ float dot64(const float* Arow, const float* v_sh) {
  float d0 = 0.f, d1 = 0.f, d2 = 0.f, d3 = 0.f;
#pragma unroll
  for (int c4 = 0; c4 < 16; ++c4) {
    float4 vv = ((const float4*)v_sh)[c4];
    d0 += Arow[c4 * 4 + 0] * vv.x;
    d1 += Arow[c4 * 4 + 1] * vv.y;
    d2 += Arow[c4 * 4 + 2] * vv.z;
    d3 += Arow[c4 * 4 + 3] * vv.w;
  }
  return (d0 + d1) + (d2 + d3);
}

__global__ __launch_bounds__(64, 1) void k_power(const float* __restrict__ v_init,
                                                 const float* __restrict__ cov,
                                                 float* __restrict__ sub) {
  const int g = blockIdx.x;
  const int r = threadIdx.x;
  __shared__ __align__(16) float v_sh[64];
  float Arow[64], Srow[64];
  const float4* crow = (const float4*)(cov + (size_t)g * 4096 + r * 64);
#pragma unroll
  for (int c4 = 0; c4 < 16; ++c4) {
    float4 cv = crow[c4];
    Arow[c4 * 4 + 0] = cv.x;
    Arow[c4 * 4 + 1] = cv.y;
    Arow[c4 * 4 + 2] = cv.z;
    Arow[c4 * 4 + 3] = cv.w;
    Srow[c4 * 4 + 0] = 0.f;
    Srow[c4 * 4 + 1] = 0.f;
    Srow[c4 * 4 + 2] = 0.f;
    Srow[c4 * 4 + 3] = 0.f;
  }

  float lam_prev = 0.f;
  for (int j = 0; j < 64; ++j) {
    // v = l2n(v_init[j])
    float v0 = v_init[((size_t)g * 64 + j) * 64 + r];
    float ss = wave_sum(v0 * v0);
    float vr = v0 / (sqrtf(ss) + 1e-12f);
    __syncthreads();
    v_sh[r] = vr;
    __syncthreads();

    for (int it = 0; it < NPI; ++it) {
      float w = dot64(Arow, v_sh);
      float s2 = wave_sum(w * w);
      vr = w / (sqrtf(s2) + 1e-12f);
      __syncthreads();
      v_sh[r] = vr;
      __syncthreads();
    }

    const float Avr = dot64(Arow, v_sh); // (A v)[r]
    const float num = wave_sum(vr * Avr);
    const float den = wave_sum(vr * vr);
    const float lam = num / den; // wave-uniform

    if (j > 0 && (lam_prev < lam || lam < EPSV)) break;

    const float sc = 1.f / sqrtf(lam);
    const float svr = sc * vr;
#pragma unroll
    for (int c4 = 0; c4 < 16; ++c4) {
      float4 vv = ((const float4*)v_sh)[c4];
      Srow[c4 * 4 + 0] += svr * vv.x;
      Srow[c4 * 4 + 1] += svr * vv.y;
      Srow[c4 * 4 + 2] += svr * vv.z;
      Srow[c4 * 4 + 3] += svr * vv.w;
      Arow[c4 * 4 + 0] -= Avr * vv.x; // A -= outer(Av, v)  (== A - A@vv^T)
      Arow[c4 * 4 + 1] -= Avr * vv.y;
      Arow[c4 * 4 + 2] -= Avr * vv.z;
      Arow[c4 * 4 + 3] -= Avr * vv.w;
    }
    lam_prev = lam;
  }

  float4* srow = (float4*)(sub + (size_t)g * 4096 + r * 64);
#pragma unroll
  for (int c4 = 0; c4 < 16; ++c4)
    srow[c4] = make_float4(Srow[c4 * 4 + 0], Srow[c4 * 4 + 1], Srow[c4 * 4 + 2],
                           Srow[c4 * 4 + 3]);
}

// ---------------------------------------------------------------------------
// Kernel D: y = (S @ (x - mu)) * weight + bias. LDS layout [ch][m] is
// conflict-free for both the staging stores and the broadcast compute reads.
// ---------------------------------------------------------------------------
__global__ __launch_bounds__(256, 2) void k_whiten(const float* __restrict__ x,
                                                   const float* __restrict__ weight,
                                                   const float* __restrict__ bias,
                                                   const float* __restrict__ mu,
                                                   const float* __restrict__ sub,
                                                   float* __restrict__ out,
                                                   int nparts) {
  const int g = blockIdx.x, n = blockIdx.y, h = blockIdx.z;
  const int tid = threadIdx.x;
  const int q = tid >> 6, l = tid & 63;
  const int ty = tid >> 4, tx = tid & 15;
  __shared__ float xs[64][68];
  __shared__ float ST[64][68]; // ST[j][i] = S[i][j]
  __shared__ float mu_sh[64];

  const float* sp = sub + (size_t)g * 4096;
#pragma unroll
  for (int r = 0; r < 16; ++r) {
    const int i = r * 4 + q;
    ST[l][i] = sp[i * 64 + l]; // coalesced load, transposed LDS store
  }
  if (tid < 64) mu_sh[tid] = mu[g * 64 + tid];

  float wgt[4], bs[4];
#pragma unroll
  for (int ii = 0; ii < 4; ++ii) {
    const int cch = g * LL + ty * 4 + ii;
    wgt[ii] = weight[cch];
    bs[ii] = bias[cch];
  }

  const float* xp = x + ((size_t)(n * CC + g * LL)) * HWS;
  float* yp = out + ((size_t)(n * CC + g * LL)) * HWS;
  const int tpp = (NTILES + nparts - 1) / nparts;
  const int t0 = h * tpp;
  const int t1 = (t0 + tpp < NTILES) ? (t0 + tpp) : NTILES;

  __syncthreads();
  for (int t = t0; t < t1; ++t) {
    const int hw0 = t * 64;
    if (t > t0) __syncthreads();
#pragma unroll
    for (int r = 0; r < 16; ++r) {
      const int ch = r * 4 + q;
      xs[ch][l] = xp[ch * HWS + hw0 + l] - mu_sh[ch]; // conflict-free store
    }
    __syncthreads();

    float acc[4][4];
#pragma unroll
    for (int ii = 0; ii < 4; ++ii)
#pragma unroll
      for (int jj = 0; jj < 4; ++jj) acc[ii][jj] = 0.f;

#pragma unroll 4
    for (int j = 0; j < 64; ++j) {
      float4 sv = ((const float4*)(&ST[j][0]))[ty]; // S[ty*4..+3][j]
      float4 xv = ((const float4*)(&xs[j][0]))[tx]; // xc[j][tx*4..+3]
      float s4[4] = {sv.x, sv.y, sv.z, sv.w};
      float x4[4] = {xv.x, xv.y, xv.z, xv.w};
#pragma unroll
      for (int ii = 0; ii < 4; ++ii)
#pragma unroll
        for (int jj = 0; jj < 4; ++jj) acc[ii][jj] += s4[ii] * x4[jj];
    }

#pragma unroll
    for (int ii = 0; ii < 4; ++ii) {
      float4 o;
      o.x = acc[ii][0] * wgt[ii] + bs[ii];
      o.y = acc[ii][1] * wgt[ii] + bs[ii];
      o.z = acc[ii][2] * wgt[ii] + bs[ii];
      o.w = acc[ii][3] * wgt[ii] + bs[ii];
      *(float4*)&yp[(ty * 4 + ii) * HWS + hw0 + tx * 4] = o;
    }
  }
}

extern "C" void kernel_launch(void* const* d_in, const int* in_sizes, int n_in,
                              void* d_out, int out_size, void* d_ws, size_t ws_size,
                              hipStream_t stream) {
  const float* x = (const float*)d_in[0];
  const float* v_init = (const float*)d_in[1];
  const float* weight = (const float*)d_in[2];
  const float* bias = (const float*)d_in[3];
  float* out = (float*)d_out;
  float* ws = (float*)d_ws;

  // ws budget: prods G*P*4096 + sums G*P*64 + mu 512 + cov G*4096 + sub G*4096
  int nparts = 2;
  size_t need2 =
      ((size_t)NG * NB * 2 * (4096 + 64) + 512 + (size_t)2 * NG * 4096) * sizeof(float);
  if (ws_size < need2) nparts = 1;

  const int P = NB * nparts;
  float* prods = ws;
  float* sums = prods + (size_t)NG * P * 4096;
  float* mu = sums + (size_t)NG * P * 64;
  float* cov = mu + 512;
  float* sub = cov + (size_t)NG * 4096;

  dim3 gA(NG, NB, nparts);
  k_moments<<<gA, 256, 0, stream>>>(x, prods, sums, nparts);
  k_cov<<<NG, 256, 0, stream>>>(prods, sums, mu, cov, nparts);
  k_power<<<NG, 64, 0, stream>>>(v_init, cov, sub);
  k_whiten<<<gA, 256, 0, stream>>>(x, weight, bias, mu, sub, out, nparts);
}

// Round 2
// 524.450 us; speedup vs baseline: 1.4602x; 1.4602x over previous
//
#include <hip/hip_runtime.h>
#include <math.h>

#define EPSV 1e-4f
#define NG 8
#define LL 64
#define NB 32
#define CC 512
#define HWS 3136
#define MTOT (NB * HWS)
#define NPI 19
#define NTILES 49

__device__ __forceinline__ float wave_sum(float v) {
#pragma unroll
  for (int off = 32; off > 0; off >>= 1) v += __shfl_xor(v, off, 64);
  return v;
}

// ---------------------------------------------------------------------------
// Kernel A: fused channel sums + raw second moments, per (group, n, part).
// LDS tile [m][ch] (pad 68 keeps float4 rows 16B aligned). Deterministic:
// partials written to ws, reduced in fixed order by k_cov.
// ---------------------------------------------------------------------------
__global__ __launch_bounds__(256, 2) void k_moments(const float* __restrict__ x,
                                                    float* __restrict__ prods,
                                                    float* __restrict__ sums,
                                                    int nparts) {
  const int g = blockIdx.x, n = blockIdx.y, h = blockIdx.z;
  const int tid = threadIdx.x;
  const int q = tid >> 6, l = tid & 63;   // load mapping
  const int ty = tid >> 4, tx = tid & 15; // compute mapping (16x16 tiles of 4x4)
  __shared__ float xs[64][68];
  const float* xp = x + ((size_t)(n * CC + g * LL)) * HWS;

  float acc[4][4];
#pragma unroll
  for (int a = 0; a < 4; ++a)
#pragma unroll
    for (int b = 0; b < 4; ++b) acc[a][b] = 0.f;
  float csum[16];
#pragma unroll
  for (int r = 0; r < 16; ++r) csum[r] = 0.f;

  const int tpp = (NTILES + nparts - 1) / nparts;
  const int t0 = h * tpp;
  const int t1 = (t0 + tpp < NTILES) ? (t0 + tpp) : NTILES;

  for (int t = t0; t < t1; ++t) {
    const int hw0 = t * 64;
    __syncthreads();
#pragma unroll
    for (int r = 0; r < 16; ++r) {
      const int ch = r * 4 + q;
      float v = xp[ch * HWS + hw0 + l]; // coalesced along hw
      xs[l][ch] = v;
      csum[r] += v;
    }
    __syncthreads();
#pragma unroll 4
    for (int mm = 0; mm < 64; ++mm) {
      const float4* row = (const float4*)(&xs[mm][0]);
      float4 av = row[ty];
      float4 bv = row[tx];
      float a4[4] = {av.x, av.y, av.z, av.w};
      float b4[4] = {bv.x, bv.y, bv.z, bv.w};
#pragma unroll
      for (int ii = 0; ii < 4; ++ii)
#pragma unroll
        for (int jj = 0; jj < 4; ++jj) acc[ii][jj] += a4[ii] * b4[jj];
    }
  }

  const int p = n * nparts + h;
  float* pp = prods + ((size_t)(g * NB * nparts + p)) * 4096;
#pragma unroll
  for (int ii = 0; ii < 4; ++ii) {
    *(float4*)&pp[(ty * 4 + ii) * 64 + tx * 4] =
        make_float4(acc[ii][0], acc[ii][1], acc[ii][2], acc[ii][3]);
  }
#pragma unroll
  for (int r = 0; r < 16; ++r) {
    float s = wave_sum(csum[r]); // sum over l within this wave (q fixed)
    if (l == 0) sums[((size_t)(g * NB * nparts + p)) * 64 + r * 4 + q] = s;
  }
}

// ---------------------------------------------------------------------------
// Kernel B1: mu[g*64+c] = sum over partials / M.  Tiny.
// ---------------------------------------------------------------------------
__global__ __launch_bounds__(64) void k_mu(const float* __restrict__ sums,
                                           float* __restrict__ mu, int P) {
  const int g = blockIdx.x;
  const int tid = threadIdx.x;
  const float* sp = sums + (size_t)g * P * 64 + tid;
  float s0 = 0.f, s1 = 0.f, s2 = 0.f, s3 = 0.f;
  int p = 0;
  for (; p + 4 <= P; p += 4) {
    s0 += sp[(size_t)(p + 0) * 64];
    s1 += sp[(size_t)(p + 1) * 64];
    s2 += sp[(size_t)(p + 2) * 64];
    s3 += sp[(size_t)(p + 3) * 64];
  }
  for (; p < P; ++p) s0 += sp[(size_t)p * 64];
  mu[g * 64 + tid] = ((s0 + s1) + (s2 + s3)) / (float)MTOT;
}

// ---------------------------------------------------------------------------
// Kernel B2: cov = S/M - mu_i mu_j + eps*I. Parallel over (group, e-chunk):
// 128 blocks x 256 threads, one element per thread, p-loop unrolled x4 for
// MLP, coalesced (consecutive e -> consecutive addresses).
// ---------------------------------------------------------------------------
__global__ __launch_bounds__(256) void k_cov(const float* __restrict__ prods,
                                             const float* __restrict__ mu,
                                             float* __restrict__ cov, int P) {
  const int g = blockIdx.x;
  const int e = blockIdx.y * 256 + threadIdx.x;
  const int i = e >> 6, j = e & 63;
  const float* pp = prods + (size_t)g * P * 4096 + e;
  float s0 = 0.f, s1 = 0.f, s2 = 0.f, s3 = 0.f;
  int p = 0;
  for (; p + 4 <= P; p += 4) {
    s0 += pp[(size_t)(p + 0) * 4096];
    s1 += pp[(size_t)(p + 1) * 4096];
    s2 += pp[(size_t)(p + 2) * 4096];
    s3 += pp[(size_t)(p + 3) * 4096];
  }
  for (; p < P; ++p) s0 += pp[(size_t)p * 4096];
  const float s = (s0 + s1) + (s2 + s3);
  const float cv =
      s / (float)MTOT - mu[g * 64 + i] * mu[g * 64 + j] + (i == j ? EPSV : 0.f);
  cov[(size_t)g * 4096 + e] = cv;
}

// ---------------------------------------------------------------------------
// Kernel C: sequential power iteration + deflation. One wave per group.
// Lane r holds row r of A and of the subspace in VGPRs; v lives in LDS
// (same-address reads = broadcast, conflict-free). Early break is exactly
// equivalent to the reference's sticky 'stopped' flag.
// ---------------------------------------------------------------------------
__device__ __forceinline__ float dot64(const float* Arow, const float* v_sh) {
  float d0 = 0.f, d1 = 0.f, d2 = 0.f, d3 = 0.f;
#pragma unroll
  for (int c4 = 0; c4 < 16; ++c4) {
    float4 vv = ((const float4*)v_sh)[c4];
    d0 += Arow[c4 * 4 + 0] * vv.x;
    d1 += Arow[c4 * 4 + 1] * vv.y;
    d2 += Arow[c4 * 4 + 2] * vv.z;
    d3 += Arow[c4 * 4 + 3] * vv.w;
  }
  return (d0 + d1) + (d2 + d3);
}

__global__ __launch_bounds__(64, 1) void k_power(const float* __restrict__ v_init,
                                                 const float* __restrict__ cov,
                                                 float* __restrict__ sub) {
  const int g = blockIdx.x;
  const int r = threadIdx.x;
  __shared__ __align__(16) float v_sh[64];
  float Arow[64], Srow[64];
  const float4* crow = (const float4*)(cov + (size_t)g * 4096 + r * 64);
#pragma unroll
  for (int c4 = 0; c4 < 16; ++c4) {
    float4 cv = crow[c4];
    Arow[c4 * 4 + 0] = cv.x;
    Arow[c4 * 4 + 1] = cv.y;
    Arow[c4 * 4 + 2] = cv.z;
    Arow[c4 * 4 + 3] = cv.w;
    Srow[c4 * 4 + 0] = 0.f;
    Srow[c4 * 4 + 1] = 0.f;
    Srow[c4 * 4 + 2] = 0.f;
    Srow[c4 * 4 + 3] = 0.f;
  }

  float lam_prev = 0.f;
  for (int j = 0; j < 64; ++j) {
    // v = l2n(v_init[j])
    float v0 = v_init[((size_t)g * 64 + j) * 64 + r];
    float ss = wave_sum(v0 * v0);
    float vr = v0 / (sqrtf(ss) + 1e-12f);
    __syncthreads();
    v_sh[r] = vr;
    __syncthreads();

    for (int it = 0; it < NPI; ++it) {
      float w = dot64(Arow, v_sh);
      float s2 = wave_sum(w * w);
      vr = w / (sqrtf(s2) + 1e-12f);
      __syncthreads();
      v_sh[r] = vr;
      __syncthreads();
    }

    const float Avr = dot64(Arow, v_sh); // (A v)[r]
    const float num = wave_sum(vr * Avr);
    const float den = wave_sum(vr * vr);
    const float lam = num / den; // wave-uniform

    if (j > 0 && (lam_prev < lam || lam < EPSV)) break;

    const float sc = 1.f / sqrtf(lam);
    const float svr = sc * vr;
#pragma unroll
    for (int c4 = 0; c4 < 16; ++c4) {
      float4 vv = ((const float4*)v_sh)[c4];
      Srow[c4 * 4 + 0] += svr * vv.x;
      Srow[c4 * 4 + 1] += svr * vv.y;
      Srow[c4 * 4 + 2] += svr * vv.z;
      Srow[c4 * 4 + 3] += svr * vv.w;
      Arow[c4 * 4 + 0] -= Avr * vv.x; // A -= outer(Av, v)  (== A - A@vv^T)
      Arow[c4 * 4 + 1] -= Avr * vv.y;
      Arow[c4 * 4 + 2] -= Avr * vv.z;
      Arow[c4 * 4 + 3] -= Avr * vv.w;
    }
    lam_prev = lam;
  }

  float4* srow = (float4*)(sub + (size_t)g * 4096 + r * 64);
#pragma unroll
  for (int c4 = 0; c4 < 16; ++c4)
    srow[c4] = make_float4(Srow[c4 * 4 + 0], Srow[c4 * 4 + 1], Srow[c4 * 4 + 2],
                           Srow[c4 * 4 + 3]);
}

// ---------------------------------------------------------------------------
// Kernel D: y = (S @ (x - mu)) * weight + bias. LDS layout [ch][m] is
// conflict-free for both the staging stores and the broadcast compute reads.
// ---------------------------------------------------------------------------
__global__ __launch_bounds__(256, 2) void k_whiten(const float* __restrict__ x,
                                                   const float* __restrict__ weight,
                                                   const float* __restrict__ bias,
                                                   const float* __restrict__ mu,
                                                   const float* __restrict__ sub,
                                                   float* __restrict__ out,
                                                   int nparts) {
  const int g = blockIdx.x, n = blockIdx.y, h = blockIdx.z;
  const int tid = threadIdx.x;
  const int q = tid >> 6, l = tid & 63;
  const int ty = tid >> 4, tx = tid & 15;
  __shared__ float xs[64][68];
  __shared__ float ST[64][68]; // ST[j][i] = S[i][j]
  __shared__ float mu_sh[64];

  const float* sp = sub + (size_t)g * 4096;
#pragma unroll
  for (int r = 0; r < 16; ++r) {
    const int i = r * 4 + q;
    ST[l][i] = sp[i * 64 + l]; // coalesced load, transposed LDS store
  }
  if (tid < 64) mu_sh[tid] = mu[g * 64 + tid];

  float wgt[4], bs[4];
#pragma unroll
  for (int ii = 0; ii < 4; ++ii) {
    const int cch = g * LL + ty * 4 + ii;
    wgt[ii] = weight[cch];
    bs[ii] = bias[cch];
  }

  const float* xp = x + ((size_t)(n * CC + g * LL)) * HWS;
  float* yp = out + ((size_t)(n * CC + g * LL)) * HWS;
  const int tpp = (NTILES + nparts - 1) / nparts;
  const int t0 = h * tpp;
  const int t1 = (t0 + tpp < NTILES) ? (t0 + tpp) : NTILES;

  __syncthreads();
  for (int t = t0; t < t1; ++t) {
    const int hw0 = t * 64;
    if (t > t0) __syncthreads();
#pragma unroll
    for (int r = 0; r < 16; ++r) {
      const int ch = r * 4 + q;
      xs[ch][l] = xp[ch * HWS + hw0 + l] - mu_sh[ch]; // conflict-free store
    }
    __syncthreads();

    float acc[4][4];
#pragma unroll
    for (int ii = 0; ii < 4; ++ii)
#pragma unroll
      for (int jj = 0; jj < 4; ++jj) acc[ii][jj] = 0.f;

#pragma unroll 4
    for (int j = 0; j < 64; ++j) {
      float4 sv = ((const float4*)(&ST[j][0]))[ty]; // S[ty*4..+3][j]
      float4 xv = ((const float4*)(&xs[j][0]))[tx]; // xc[j][tx*4..+3]
      float s4[4] = {sv.x, sv.y, sv.z, sv.w};
      float x4[4] = {xv.x, xv.y, xv.z, xv.w};
#pragma unroll
      for (int ii = 0; ii < 4; ++ii)
#pragma unroll
        for (int jj = 0; jj < 4; ++jj) acc[ii][jj] += s4[ii] * x4[jj];
    }

#pragma unroll
    for (int ii = 0; ii < 4; ++ii) {
      float4 o;
      o.x = acc[ii][0] * wgt[ii] + bs[ii];
      o.y = acc[ii][1] * wgt[ii] + bs[ii];
      o.z = acc[ii][2] * wgt[ii] + bs[ii];
      o.w = acc[ii][3] * wgt[ii] + bs[ii];
      *(float4*)&yp[(ty * 4 + ii) * HWS + hw0 + tx * 4] = o;
    }
  }
}

extern "C" void kernel_launch(void* const* d_in, const int* in_sizes, int n_in,
                              void* d_out, int out_size, void* d_ws, size_t ws_size,
                              hipStream_t stream) {
  const float* x = (const float*)d_in[0];
  const float* v_init = (const float*)d_in[1];
  const float* weight = (const float*)d_in[2];
  const float* bias = (const float*)d_in[3];
  float* out = (float*)d_out;
  float* ws = (float*)d_ws;

  // ws budget: prods G*P*4096 + sums G*P*64 + mu 512 + cov G*4096 + sub G*4096
  int nparts = 2;
  size_t need2 =
      ((size_t)NG * NB * 2 * (4096 + 64) + 512 + (size_t)2 * NG * 4096) * sizeof(float);
  if (ws_size < need2) nparts = 1;

  const int P = NB * nparts;
  float* prods = ws;
  float* sums = prods + (size_t)NG * P * 4096;
  float* mu = sums + (size_t)NG * P * 64;
  float* cov = mu + 512;
  float* sub = cov + (size_t)NG * 4096;

  dim3 gA(NG, NB, nparts);
  k_moments<<<gA, 256, 0, stream>>>(x, prods, sums, nparts);
  k_mu<<<NG, 64, 0, stream>>>(sums, mu, P);
  k_cov<<<dim3(NG, 16), 256, 0, stream>>>(prods, mu, cov, P);
  k_power<<<NG, 64, 0, stream>>>(v_init, cov, sub);
  k_whiten<<<gA, 256, 0, stream>>>(x, weight, bias, mu, sub, out, nparts);
}